// Round 7
// baseline (372.796 us; speedup 1.0000x reference)
//
#include <hip/hip_runtime.h>
#include <math.h>

#define MID 512
#define KT  16
#define NB  65536
#define G   4096
#define PTS 4128   // 258 blocks * 16 points; table point p holds x = (p-1)/G

struct NetP { const float *w1,*b1,*w2,*b2,*w3,*b3; };
struct AllP { NetP n[3]; float* table; };

// ---------------------------------------------------------------------------
// Kernel 0: transpose W2 (512x512) -> W2T[k][n], per net, so k_siren staging
// is coalesced-global b128 + linear b128 LDS writes.
// ---------------------------------------------------------------------------
__global__ __launch_bounds__(256)
void k_prep(AllP P, float* __restrict__ w2t)
{
    __shared__ float t[32][33];
    const int net = blockIdx.z;
    const float* src = (net == 0) ? P.n[0].w2 : (net == 1) ? P.n[1].w2 : P.n[2].w2;
    float* dst = w2t + (size_t)net * MID * MID;
    const int bx = blockIdx.x * 32, by = blockIdx.y * 32;
    const int tx = threadIdx.x & 31, ty = threadIdx.x >> 5;   // ty 0..7
    #pragma unroll
    for (int j = 0; j < 4; ++j)
        t[ty + 8 * j][tx] = src[(size_t)(by + ty + 8 * j) * MID + bx + tx];
    __syncthreads();
    #pragma unroll
    for (int j = 0; j < 4; ++j)
        dst[(size_t)(bx + ty + 8 * j) * MID + by + tx] = t[tx][ty + 8 * j];
}

// ---------------------------------------------------------------------------
// Kernel 1: fused SIREN net at 16 grid points per block, 512 threads (8 waves),
// 258 blocks x 3 nets = 774 blocks (3 blocks/CU, balanced).
// Thread (pg = tid>>6, c = tid&63): points pg*2..+1, cols {c*4, 256+c*4}.
// W2T slab staged with coalesced b128 loads + linear b128 LDS writes.
// acc = 4 named float4 (16 VGPR). Layer 3 fused, XOR-swizzled LDS.
// ---------------------------------------------------------------------------
__global__ __attribute__((amdgpu_waves_per_eu(2, 8))) __launch_bounds__(512)
void k_siren(AllP P, const float* __restrict__ w2t)
{
    __shared__ float smemA[KT * MID];   // 32 KB: W2T slab [kt][n] / layer3 h2
    __shared__ float hlds[KT * 16];     // 1 KB: h1 slab [kt][m]
    __shared__ float xs[16];

    const int tid = threadIdx.x;
    const int net = blockIdx.y;
    const int m0  = blockIdx.x * 16;
    NetP np;
    if (net == 0)      np = P.n[0];
    else if (net == 1) np = P.n[1];
    else               np = P.n[2];
    const float* wslab = w2t + (size_t)net * MID * MID;

    if (tid < 16) xs[tid] = ((float)(m0 + tid) - 1.0f) * (1.0f / (float)G);
    __syncthreads();

    const int c   = tid & 63;
    const int pg  = tid >> 6;    // wave id 0..7 -> points pg*2, pg*2+1
    const int skt = tid >> 5;    // staging slab row 0..15
    const int sch = tid & 31;    // staging chunk (16 floats each)

    float4 a0lo = make_float4(0.f,0.f,0.f,0.f), a0hi = make_float4(0.f,0.f,0.f,0.f);
    float4 a1lo = make_float4(0.f,0.f,0.f,0.f), a1hi = make_float4(0.f,0.f,0.f,0.f);

#define FMA8(i, hv) \
        a##i##lo.x = fmaf(hv, wa.x, a##i##lo.x); a##i##lo.y = fmaf(hv, wa.y, a##i##lo.y); \
        a##i##lo.z = fmaf(hv, wa.z, a##i##lo.z); a##i##lo.w = fmaf(hv, wa.w, a##i##lo.w); \
        a##i##hi.x = fmaf(hv, wb.x, a##i##hi.x); a##i##hi.y = fmaf(hv, wb.y, a##i##hi.y); \
        a##i##hi.z = fmaf(hv, wb.z, a##i##hi.z); a##i##hi.w = fmaf(hv, wb.w, a##i##hi.w);

    for (int ks = 0; ks < MID / KT; ++ks) {
        const int k0 = ks * KT;

        if (tid < 256) {   // h1 slab: 256 entries
            const int kt = tid >> 4, m = tid & 15;
            const float zz = 4.f * fmaf(xs[m], np.w1[k0 + kt], np.b1[k0 + kt]);
            hlds[kt * 16 + m] = sinf(sinf(zz));
        }
        {   // W2T slab [kt][n]: coalesced reads, linear b128 writes
            const float* wr = wslab + (size_t)(k0 + skt) * MID + sch * 16;
            const float4 v0 = *reinterpret_cast<const float4*>(wr + 0);
            const float4 v1 = *reinterpret_cast<const float4*>(wr + 4);
            const float4 v2 = *reinterpret_cast<const float4*>(wr + 8);
            const float4 v3 = *reinterpret_cast<const float4*>(wr + 12);
            float* sd = &smemA[skt * MID + sch * 16];
            *reinterpret_cast<float4*>(sd + 0)  = v0;
            *reinterpret_cast<float4*>(sd + 4)  = v1;
            *reinterpret_cast<float4*>(sd + 8)  = v2;
            *reinterpret_cast<float4*>(sd + 12) = v3;
        }
        __syncthreads();

        #pragma unroll
        for (int kt = 0; kt < KT; ++kt) {
            const float2 h  = *reinterpret_cast<const float2*>(&hlds[kt * 16 + pg * 2]);
            const float4 wa = *reinterpret_cast<const float4*>(&smemA[kt * MID + c * 4]);
            const float4 wb = *reinterpret_cast<const float4*>(&smemA[kt * MID + 256 + c * 4]);
            FMA8(0, h.x) FMA8(1, h.y)
        }
        __syncthreads();
    }

    {   // epilogue: h2 = sin(sin(4*(z + b2)))
        const float4 ba = *reinterpret_cast<const float4*>(np.b2 + c * 4);
        const float4 bb = *reinterpret_cast<const float4*>(np.b2 + 256 + c * 4);
#define SS1(v, b) v = sinf(sinf(4.f * ((v) + (b))));
#define SSROW(i) \
        SS1(a##i##lo.x, ba.x) SS1(a##i##lo.y, ba.y) SS1(a##i##lo.z, ba.z) SS1(a##i##lo.w, ba.w) \
        SS1(a##i##hi.x, bb.x) SS1(a##i##hi.y, bb.y) SS1(a##i##hi.z, bb.z) SS1(a##i##hi.w, bb.w)
        SSROW(0) SSROW(1)
    }

    // layer 3: two half-passes (cols 0..255 = lo, 256..511 = hi)
    const int m  = tid & 15;    // point
    const int jg = tid >> 4;    // 0..31 -> output col jg
    const float* wrow3 = np.w3 + (size_t)jg * MID;
    float acc3a = 0.f, acc3b = 0.f;

#define L3STORE(i, sfx) { const int mr = pg * 2 + i; \
    *reinterpret_cast<float4*>(&smemA[mr * 256 + (c ^ mr) * 4]) = a##i##sfx; }

#define L3PASS(p, sfx) { \
    L3STORE(0, sfx) L3STORE(1, sfx) \
    __syncthreads(); \
    _Pragma("unroll 8") \
    for (int qq = 0; qq < 64; ++qq) { \
        const float4 h = *reinterpret_cast<const float4*>(&smemA[m * 256 + ((qq ^ m) & 63) * 4]); \
        const float4 w = *reinterpret_cast<const float4*>(wrow3 + (p) * 256 + qq * 4); \
        acc3a = fmaf(h.y, w.y, fmaf(h.x, w.x, acc3a)); \
        acc3b = fmaf(h.w, w.w, fmaf(h.z, w.z, acc3b)); \
    } \
    __syncthreads(); }

    L3PASS(0, lo)
    L3PASS(1, hi)

    P.table[((size_t)net * PTS + (m0 + m)) * 32 + jg] = acc3a + acc3b + np.b3[jg];
}

// ---------------------------------------------------------------------------
// Kernel 2: Catmull-Rom interp + Tucker contraction. 4 threads/sample
// (rh wave-uniform -> core LDS reads are broadcasts), 64 samples/block.
// Inner reduction split into 4 parallel FMA chains + 2-way tracc chains
// (round-6 version was a 32-deep dependent chain per s: latency-bound).
// ---------------------------------------------------------------------------
#define F4MA(acc, s, rp, k) { const float4 _v = (rp)[k]; \
    acc.x = fmaf((s), _v.x, acc.x); acc.y = fmaf((s), _v.y, acc.y); \
    acc.z = fmaf((s), _v.z, acc.z); acc.w = fmaf((s), _v.w, acc.w); }

#define GROW8(Pfx, w, rp, off) \
    F4MA(Pfx##0,(w),rp,(off)+0) F4MA(Pfx##1,(w),rp,(off)+1) \
    F4MA(Pfx##2,(w),rp,(off)+2) F4MA(Pfx##3,(w),rp,(off)+3) \
    F4MA(Pfx##4,(w),rp,(off)+4) F4MA(Pfx##5,(w),rp,(off)+5) \
    F4MA(Pfx##6,(w),rp,(off)+6) F4MA(Pfx##7,(w),rp,(off)+7)

// Catmull-Rom setup: x*G is EXACT in fp32 (power-of-two scale).
#define CRSETUP(x_, iv, c0, c1, c2, c3) \
    int iv; float c0, c1, c2, c3; { \
        float xx = (x_) * (float)G; \
        int i = (int)xx; i = i < 0 ? 0 : (i > G - 1 ? G - 1 : i); iv = i; \
        float t = xx - (float)i; \
        float t2 = t * t, t3 = t2 * t; \
        c0 = fmaf(-0.5f, t3, t2) - 0.5f * t; \
        c1 = fmaf(1.5f, t3, fmaf(-2.5f, t2, 1.f)); \
        c2 = fmaf(-1.5f, t3, fmaf(2.f, t2, 0.5f * t)); \
        c3 = 0.5f * (t3 - t2); }

__global__ __attribute__((amdgpu_waves_per_eu(2, 4))) __launch_bounds__(256)
void k_ic(const float* __restrict__ table, const float* __restrict__ core,
          const float* __restrict__ x, float* __restrict__ out)
{
    __shared__ float cs[8 * 1024];   // 32 KB: 8 r-rows of C per round
    __shared__ float red[256];

    const int tid = threadIdx.x;
    const int ls  = tid & 63;        // local sample
    const int rh  = tid >> 6;        // 0..3, wave-uniform; r = rb*8+rh*2+{0,1}
    const int g   = blockIdx.x * 64 + ls;

    const float xu = x[(size_t)g * 3 + 0];
    const float xv = x[(size_t)g * 3 + 1];
    const float xw = x[(size_t)g * 3 + 2];

#define DECLZ(Pn) float4 Pn = make_float4(0.f,0.f,0.f,0.f);
    DECLZ(W0) DECLZ(W1) DECLZ(W2) DECLZ(W3) DECLZ(W4) DECLZ(W5) DECLZ(W6) DECLZ(W7)
    DECLZ(V0) DECLZ(V1) DECLZ(V2) DECLZ(V3) DECLZ(V4) DECLZ(V5) DECLZ(V6) DECLZ(V7)
    float2 U0, U1, U2, U3;

    {   // W net (index 2)
        CRSETUP(xw, iw, c0, c1, c2, c3)
        const float4* rp = reinterpret_cast<const float4*>(
            table + ((size_t)2 * PTS + iw) * 32);
        GROW8(W, c0, rp, 0) GROW8(W, c1, rp, 8) GROW8(W, c2, rp, 16) GROW8(W, c3, rp, 24)
    }
    {   // V net (index 1)
        CRSETUP(xv, iv2, c0, c1, c2, c3)
        const float4* rp = reinterpret_cast<const float4*>(
            table + ((size_t)1 * PTS + iv2) * 32);
        GROW8(V, c0, rp, 0) GROW8(V, c1, rp, 8) GROW8(V, c2, rp, 16) GROW8(V, c3, rp, 24)
    }
    {   // U net (index 0): this thread's 8 r-cols = rb*8 + rh*2 + {0,1}
        CRSETUP(xu, iu, c0, c1, c2, c3)
        const float2* up = reinterpret_cast<const float2*>(table + (size_t)iu * 32);
#define UROW(rbv, dst) { \
        const float2 t0 = up[0 * 16 + (rbv) * 4 + rh]; \
        const float2 t1 = up[1 * 16 + (rbv) * 4 + rh]; \
        const float2 t2 = up[2 * 16 + (rbv) * 4 + rh]; \
        const float2 t3 = up[3 * 16 + (rbv) * 4 + rh]; \
        dst.x = fmaf(c0,t0.x,fmaf(c1,t1.x,fmaf(c2,t2.x,c3*t3.x))); \
        dst.y = fmaf(c0,t0.y,fmaf(c1,t1.y,fmaf(c2,t2.y,c3*t3.y))); }
        UROW(0, U0) UROW(1, U1) UROW(2, U2) UROW(3, U3)
    }

#define TQ2(rl, s, tq, Wv, aa) { \
    const float4 c4 = *reinterpret_cast<const float4*>( \
        &cs[(rh * 2 + (rl)) * 1024 + (s) * 32 + (tq) * 4]); \
    aa = fmaf(Wv.w, c4.w, fmaf(Wv.z, c4.z, fmaf(Wv.y, c4.y, fmaf(Wv.x, c4.x, aa)))); }

#define SONE(rl, s, vcomp, tr) { float aaA=0.f, aaB=0.f, aaC=0.f, aaD=0.f; \
    TQ2(rl, s, 0, W0, aaA) TQ2(rl, s, 1, W1, aaB) \
    TQ2(rl, s, 2, W2, aaC) TQ2(rl, s, 3, W3, aaD) \
    TQ2(rl, s, 4, W4, aaA) TQ2(rl, s, 5, W5, aaB) \
    TQ2(rl, s, 6, W6, aaC) TQ2(rl, s, 7, W7, aaD) \
    tr = fmaf(vcomp, (aaA + aaB) + (aaC + aaD), tr); }

#define SG(rl, sb, Vv) \
    SONE(rl, 4*(sb)+0, Vv.x, trA) SONE(rl, 4*(sb)+1, Vv.y, trB) \
    SONE(rl, 4*(sb)+2, Vv.z, trA) SONE(rl, 4*(sb)+3, Vv.w, trB)

#define RL1(rl, ucomp) { float trA = 0.f, trB = 0.f; \
    SG(rl, 0, V0) SG(rl, 1, V1) SG(rl, 2, V2) SG(rl, 3, V3) \
    SG(rl, 4, V4) SG(rl, 5, V5) SG(rl, 6, V6) SG(rl, 7, V7) \
    o = fmaf(ucomp, trA + trB, o); }

#define RBLOCK(rb) { \
    __syncthreads(); \
    _Pragma("unroll") \
    for (int cc = 0; cc < 8; ++cc) \
        *reinterpret_cast<float4*>(&cs[cc * 1024 + tid * 4]) = \
            *reinterpret_cast<const float4*>(core + (size_t)((rb) * 8 + cc) * 1024 + tid * 4); \
    __syncthreads(); \
    RL1(0, U##rb.x) RL1(1, U##rb.y) }

    float o = 0.f;
    RBLOCK(0) RBLOCK(1) RBLOCK(2) RBLOCK(3)

    red[tid] = o;
    __syncthreads();
    if (tid < 64)
        out[blockIdx.x * 64 + tid] =
            red[tid] + red[tid + 64] + red[tid + 128] + red[tid + 192];
}

// ---------------------------------------------------------------------------
extern "C" void kernel_launch(void* const* d_in, const int* in_sizes, int n_in,
                              void* d_out, int out_size, void* d_ws, size_t ws_size,
                              hipStream_t stream)
{
    AllP P;
    for (int net = 0; net < 3; ++net) {
        const int b = 1 + net * 6;
        P.n[net].w1 = (const float*)d_in[b + 0];
        P.n[net].b1 = (const float*)d_in[b + 1];
        P.n[net].w2 = (const float*)d_in[b + 2];
        P.n[net].b2 = (const float*)d_in[b + 3];
        P.n[net].w3 = (const float*)d_in[b + 4];
        P.n[net].b3 = (const float*)d_in[b + 5];
    }
    const float* xin  = (const float*)d_in[0];
    const float* core = (const float*)d_in[19];
    float* wsf   = (float*)d_ws;
    float* table = wsf;                          // 3*4128*32 floats = 1.58 MB
    float* w2t   = wsf + (size_t)3 * PTS * 32;   // 3*512*512 floats = 3.0 MB
    P.table = table;

    k_prep <<<dim3(16, 16, 3), 256, 0, stream>>>(P, w2t);
    k_siren<<<dim3(PTS / 16, 3), 512, 0, stream>>>(P, w2t);
    k_ic   <<<NB / 64, 256, 0, stream>>>(table, core, xin, (float*)d_out);
}